// Round 3
// baseline (1314.165 us; speedup 1.0000x reference)
//
#include <hip/hip_runtime.h>
#include <cstdint>

typedef unsigned short u16;
typedef __bf16 bf16x8 __attribute__((ext_vector_type(8)));
typedef float f32x4 __attribute__((ext_vector_type(4)));

__device__ __forceinline__ float bf2f(u16 h) {
  union { uint32_t u; float f; } v; v.u = (uint32_t)h << 16; return v.f;
}
__device__ __forceinline__ u16 f2bf(float f) {
  union { float f; uint32_t u; } v; v.f = f;
  uint32_t r = v.u + 0x7fffu + ((v.u >> 16) & 1u);
  return (u16)(r >> 16);
}
__device__ __forceinline__ float sigmoidf_(float x) {
  return 1.0f / (1.0f + __expf(-x));
}
__device__ __forceinline__ void load_lds16(const void* g, void* l) {
  __builtin_amdgcn_global_load_lds(
      (const __attribute__((address_space(1))) void*)g,
      (__attribute__((address_space(3))) void*)l, 16, 0, 0);
}

// ---------------- flat convert f32 -> bf16 (n multiple of 4) -------------
__global__ __launch_bounds__(256) void cvt_f2b(const float* __restrict__ in,
                                               u16* __restrict__ out) {
  long i = ((long)blockIdx.x * 256 + threadIdx.x) * 4;
  float4 v = *(const float4*)(in + i);
  uint2 o;
  o.x = (uint32_t)f2bf(v.x) | ((uint32_t)f2bf(v.y) << 16);
  o.y = (uint32_t)f2bf(v.z) | ((uint32_t)f2bf(v.w) << 16);
  *((uint2*)(out + i)) = o;
}

// ------------- transpose+convert: in f32 [K][N] -> out bf16 [N][K] -------
__global__ __launch_bounds__(256) void transpose_cvt(
    const float* __restrict__ in, u16* __restrict__ out, int K, int N) {
  __shared__ float t[32][33];
  int n0 = blockIdx.x * 32, k0 = blockIdx.y * 32;
  int tx = threadIdx.x & 31, ty = threadIdx.x >> 5;
#pragma unroll
  for (int i = 0; i < 32; i += 8)
    t[ty + i][tx] = in[(long)(k0 + ty + i) * N + n0 + tx];
  __syncthreads();
#pragma unroll
  for (int i = 0; i < 32; i += 8)
    out[(long)(n0 + ty + i) * K + k0 + tx] = f2bf(t[tx][ty + i]);
}

// ------- q/k projection: [T,1024]f32 @ [1024,16]f32 + b -> f32 [T,16] ----
__global__ __launch_bounds__(256) void proj16(const float* __restrict__ in,
                                              const float* __restrict__ w,
                                              const float* __restrict__ b,
                                              float* __restrict__ out) {
  int tid = threadIdx.x;
  long t0 = (long)blockIdx.x * 16;
  int col = tid & 15, tok = tid >> 4;
  const float* xr = in + (t0 + tok) * 1024;
  float acc = 0.f;
  for (int k = 0; k < 1024; k += 4) {
    float4 xv = *(const float4*)(xr + k);
    acc += xv.x * w[(long)k * 16 + col];
    acc += xv.y * w[(long)(k + 1) * 16 + col];
    acc += xv.z * w[(long)(k + 2) * 16 + col];
    acc += xv.w * w[(long)(k + 3) * 16 + col];
  }
  out[(t0 + tok) * 16 + col] = acc + b[col];
}

// -------- MFMA GEMM: C[M,N] = act(A[M,K]bf16 @ BT[N,K]^T + bias_f32) -----
// F32OUT=1 -> C is float*, else bf16 (u16*)
template <int ACT, int F32OUT>
__global__ __launch_bounds__(256) void gemm_bt(
    const u16* __restrict__ A, const u16* __restrict__ BT,
    const float* __restrict__ bias, void* __restrict__ Cv, int M, int N,
    int K) {
  __shared__ __attribute__((aligned(16))) u16 sA[2][128 * 32];
  __shared__ __attribute__((aligned(16))) u16 sB[2][128 * 32];
  const int tid = threadIdx.x;
  const int wave = tid >> 6, lane = tid & 63;
  const long bm = (long)blockIdx.y * 128, bn = (long)blockIdx.x * 128;
  const int wr = (wave >> 1) * 64, wc = (wave & 1) * 64;
  const int lrow = lane & 15, g = lane >> 4;

  f32x4 acc[4][4] = {};

  const int KT = K >> 5;
  auto stage = [&](int buf, int kt) {
    const u16* Ab = A + bm * K + (long)kt * 32;
    const u16* Bb = BT + bn * K + (long)kt * 32;
#pragma unroll
    for (int r = 0; r < 2; r++) {
      int slot0 = (r * 4 + wave) * 64;
      int slot = slot0 + lane;
      long row = slot >> 2;
      int kg = slot & 3;
      load_lds16(Ab + row * K + kg * 8, &sA[buf][slot0 * 8]);
      load_lds16(Bb + row * K + kg * 8, &sB[buf][slot0 * 8]);
    }
  };
  stage(0, 0);
  __syncthreads();
  for (int kt = 0; kt < KT; kt++) {
    int cur = kt & 1;
    if (kt + 1 < KT) stage(cur ^ 1, kt + 1);
    bf16x8 af[4], bfr[4];
#pragma unroll
    for (int m = 0; m < 4; m++)
      af[m] = *(const bf16x8*)&sA[cur][(wr + m * 16 + lrow) * 32 + g * 8];
#pragma unroll
    for (int n = 0; n < 4; n++)
      bfr[n] = *(const bf16x8*)&sB[cur][(wc + n * 16 + lrow) * 32 + g * 8];
#pragma unroll
    for (int m = 0; m < 4; m++)
#pragma unroll
      for (int n = 0; n < 4; n++)
        acc[m][n] = __builtin_amdgcn_mfma_f32_16x16x32_bf16(af[m], bfr[n],
                                                            acc[m][n], 0, 0, 0);
    __syncthreads();
  }
#pragma unroll
  for (int m = 0; m < 4; m++) {
#pragma unroll
    for (int n = 0; n < 4; n++) {
      long col = bn + wc + n * 16 + lrow;
      float bb = bias[col];
#pragma unroll
      for (int i = 0; i < 4; i++) {
        long row = bm + wr + m * 16 + g * 4 + i;
        float v = acc[m][n][i] + bb;
        if (ACT == 1) v = fmaxf(v, 0.f);
        if (F32OUT)
          ((float*)Cv)[row * N + col] = v;
        else
          ((u16*)Cv)[row * N + col] = f2bf(v);
      }
    }
  }
}

// -- kv partial: part[b,h,sc,d] = sum_{s in chunk} sig(k)*v  (v bf16) -----
__global__ __launch_bounds__(256) void kv_part(const float* __restrict__ kp,
                                               const u16* __restrict__ v,
                                               float* __restrict__ part) {
  int bid = blockIdx.x;
  int sc = bid & 7, h = (bid >> 3) & 15, b = bid >> 7;
  int d = threadIdx.x & 63, si = threadIdx.x >> 6;
  float acc = 0.f;
  int s0 = sc * 512;
  for (int s = s0 + si; s < s0 + 512; s += 4) {
    long tok = (long)b * 4096 + s;
    float sk = sigmoidf_(kp[tok * 16 + h]);
    acc += sk * bf2f(v[tok * 1024 + h * 64 + d]);
  }
  __shared__ float red[4][64];
  red[si][d] = acc;
  __syncthreads();
  if (si == 0)
    part[(long)bid * 64 + d] = red[0][d] + red[1][d] + red[2][d] + red[3][d];
}

// ---------------- reduce chunks + cumsum over heads ----------------------
__global__ __launch_bounds__(64) void kv_finish(const float* __restrict__ part,
                                                float* __restrict__ scum) {
  int b = blockIdx.x, d = threadIdx.x;
  float run = 0.f;
  for (int h = 0; h < 16; h++) {
    float s = 0.f;
    for (int sc = 0; sc < 8; sc++)
      s += part[(((long)b * 16 + h) * 8 + sc) * 64 + d];
    run += s;
    scum[((long)b * 16 + h) * 64 + d] = run;
  }
}

// ------- pre[t, h*64+d] = sigmoid(q[t,h]) * scum[b,h,d]  -> bf16 ---------
__global__ __launch_bounds__(256) void premul(const float* __restrict__ qp,
                                              const float* __restrict__ scum,
                                              u16* __restrict__ out) {
  long idx = ((long)blockIdx.x * 256 + threadIdx.x) * 8;
  long tok = idx >> 10;
  int c = (int)(idx & 1023);
  int h = c >> 6, d0 = c & 63;
  int b = (int)(tok >> 12);
  float sq = sigmoidf_(qp[tok * 16 + h]);
  const float* sp = scum + ((long)b * 16 + h) * 64 + d0;
  uint4 o;
  o.x = (uint32_t)f2bf(sq * sp[0]) | ((uint32_t)f2bf(sq * sp[1]) << 16);
  o.y = (uint32_t)f2bf(sq * sp[2]) | ((uint32_t)f2bf(sq * sp[3]) << 16);
  o.z = (uint32_t)f2bf(sq * sp[4]) | ((uint32_t)f2bf(sq * sp[5]) << 16);
  o.w = (uint32_t)f2bf(sq * sp[6]) | ((uint32_t)f2bf(sq * sp[7]) << 16);
  *((uint4*)(out + idx)) = o;
}

// --- out_f32 = LayerNorm(a_bf16 + r_f32)*g + be ; optional bf16 copy -----
__global__ __launch_bounds__(256) void ln_res(const u16* __restrict__ a,
                                              const float* __restrict__ r,
                                              const float* __restrict__ g,
                                              const float* __restrict__ be,
                                              float* __restrict__ out,
                                              u16* __restrict__ outb) {
  long row = blockIdx.x;
  int tid = threadIdx.x;
  uint2 av = ((const uint2*)(a + row * 1024))[tid];
  float4 rv = ((const float4*)(r + row * 1024))[tid];
  float y[4];
  y[0] = bf2f((u16)(av.x & 0xffff)) + rv.x;
  y[1] = bf2f((u16)(av.x >> 16)) + rv.y;
  y[2] = bf2f((u16)(av.y & 0xffff)) + rv.z;
  y[3] = bf2f((u16)(av.y >> 16)) + rv.w;
  float s = y[0] + y[1] + y[2] + y[3];
  float q = y[0] * y[0] + y[1] * y[1] + y[2] * y[2] + y[3] * y[3];
#pragma unroll
  for (int o = 32; o > 0; o >>= 1) {
    s += __shfl_down(s, o);
    q += __shfl_down(q, o);
  }
  __shared__ float s1[4], s2[4];
  int wid = tid >> 6, lane = tid & 63;
  if (lane == 0) { s1[wid] = s; s2[wid] = q; }
  __syncthreads();
  s = s1[0] + s1[1] + s1[2] + s1[3];
  q = s2[0] + s2[1] + s2[2] + s2[3];
  float mu = s * (1.f / 1024.f);
  float var = q * (1.f / 1024.f) - mu * mu;
  float inv = rsqrtf(fmaxf(var, 0.f) + 1e-6f);
  float4 gv = ((const float4*)g)[tid], bv = ((const float4*)be)[tid];
  float o0 = gv.x * (y[0] - mu) * inv + bv.x;
  float o1 = gv.y * (y[1] - mu) * inv + bv.y;
  float o2 = gv.z * (y[2] - mu) * inv + bv.z;
  float o3 = gv.w * (y[3] - mu) * inv + bv.w;
  float4 ov = make_float4(o0, o1, o2, o3);
  ((float4*)(out + row * 1024))[tid] = ov;
  if (outb != nullptr) {
    uint2 ob;
    ob.x = (uint32_t)f2bf(o0) | ((uint32_t)f2bf(o1) << 16);
    ob.y = (uint32_t)f2bf(o2) | ((uint32_t)f2bf(o3) << 16);
    ((uint2*)(outb + row * 1024))[tid] = ob;
  }
}

extern "C" void kernel_launch(void* const* d_in, const int* in_sizes, int n_in,
                              void* d_out, int out_size, void* d_ws,
                              size_t ws_size, hipStream_t stream) {
  const float* x   = (const float*)d_in[0];
  const float* enc = (const float*)d_in[1];
  const float* wq1 = (const float*)d_in[2];  const float* bq1 = (const float*)d_in[3];
  const float* wk1 = (const float*)d_in[4];  const float* bk1 = (const float*)d_in[5];
  const float* wv1 = (const float*)d_in[6];  const float* bv1 = (const float*)d_in[7];
  const float* wo1 = (const float*)d_in[8];  const float* bo1 = (const float*)d_in[9];
  const float* wq2 = (const float*)d_in[10]; const float* bq2 = (const float*)d_in[11];
  const float* wk2 = (const float*)d_in[12]; const float* bk2 = (const float*)d_in[13];
  const float* wv2 = (const float*)d_in[14]; const float* bv2 = (const float*)d_in[15];
  const float* wo2 = (const float*)d_in[16]; const float* bo2 = (const float*)d_in[17];
  const float* wf1 = (const float*)d_in[18]; const float* bf1 = (const float*)d_in[19];
  const float* wf2 = (const float*)d_in[20]; const float* bf2 = (const float*)d_in[21];
  const float* g1 = (const float*)d_in[22];  const float* be1 = (const float*)d_in[23];
  const float* g2 = (const float*)d_in[24];  const float* be2 = (const float*)d_in[25];
  const float* g3 = (const float*)d_in[26];  const float* be3 = (const float*)d_in[27];
  (void)in_sizes; (void)n_in; (void)out_size; (void)ws_size;

  const size_t S = (size_t)16384 * 1024;  // tokens * d_model
  float* O0 = (float*)d_out;      // out3
  float* O1 = O0 + S;             // scratch for out1 (f32), zeroed at end
  float* O2 = O0 + 2 * S;         // scratch for out2 (f32), zeroed at end

  char* base = (char*)d_ws;
  size_t off = 0;
  auto alloc = [&](size_t bytes) -> void* {
    void* p = base + off;
    off += (bytes + 255) & ~(size_t)255;
    return p;
  };
  u16* WT1  = (u16*)alloc((size_t)4096 * 1024 * 2);   // weight^T bf16
  u16* WT2  = (u16*)alloc((size_t)4096 * 1024 * 2);
  float* qb = (float*)alloc((size_t)16384 * 16 * 4);
  float* kb = (float*)alloc((size_t)16384 * 16 * 4);
  float* kvp = (float*)alloc((size_t)512 * 64 * 4);
  float* scm = (float*)alloc((size_t)4 * 16 * 64 * 4);
  u16* FA = (u16*)alloc(S * 2);   // bf16: v / attn / ffn_out
  u16* FB = (u16*)alloc(S * 2);   // bf16: pre / ffn mid (chunked)
  u16* XB = (u16*)alloc(S * 2);   // bf16: x / enc / out2

  const int T = 16384;
  dim3 blk(256);

  // ---- MHA1 (q=k=v from x) ----
  cvt_f2b<<<16384, blk, 0, stream>>>(x, XB);
  transpose_cvt<<<dim3(32, 32), blk, 0, stream>>>(wv1, WT1, 1024, 1024);
  gemm_bt<0, 0><<<dim3(8, 128), blk, 0, stream>>>(XB, WT1, bv1, FA, T, 1024, 1024);
  proj16<<<1024, blk, 0, stream>>>(x, wq1, bq1, qb);
  proj16<<<1024, blk, 0, stream>>>(x, wk1, bk1, kb);
  kv_part<<<512, blk, 0, stream>>>(kb, FA, kvp);
  kv_finish<<<4, 64, 0, stream>>>(kvp, scm);
  premul<<<8192, blk, 0, stream>>>(qb, scm, FB);
  transpose_cvt<<<dim3(32, 32), blk, 0, stream>>>(wo1, WT1, 1024, 1024);
  gemm_bt<0, 0><<<dim3(8, 128), blk, 0, stream>>>(FB, WT1, bo1, FA, T, 1024, 1024);
  ln_res<<<16384, blk, 0, stream>>>(FA, x, g1, be1, O1, nullptr);  // out1

  // ---- MHA2 (q from out1, k/v from enc) ----
  cvt_f2b<<<16384, blk, 0, stream>>>(enc, XB);
  transpose_cvt<<<dim3(32, 32), blk, 0, stream>>>(wv2, WT1, 1024, 1024);
  gemm_bt<0, 0><<<dim3(8, 128), blk, 0, stream>>>(XB, WT1, bv2, FA, T, 1024, 1024);
  proj16<<<1024, blk, 0, stream>>>(O1, wq2, bq2, qb);
  proj16<<<1024, blk, 0, stream>>>(enc, wk2, bk2, kb);
  kv_part<<<512, blk, 0, stream>>>(kb, FA, kvp);
  kv_finish<<<4, 64, 0, stream>>>(kvp, scm);
  premul<<<8192, blk, 0, stream>>>(qb, scm, FB);
  transpose_cvt<<<dim3(32, 32), blk, 0, stream>>>(wo2, WT1, 1024, 1024);
  gemm_bt<0, 0><<<dim3(8, 128), blk, 0, stream>>>(FB, WT1, bo2, FA, T, 1024, 1024);
  ln_res<<<16384, blk, 0, stream>>>(FA, O1, g2, be2, O2, XB);  // out2 (+bf16)

  // ---- FFN (4 chunks of 4096 tokens; mid reuses FB) ----
  transpose_cvt<<<dim3(128, 32), blk, 0, stream>>>(wf1, WT1, 1024, 4096);
  transpose_cvt<<<dim3(32, 128), blk, 0, stream>>>(wf2, WT2, 4096, 1024);
  for (int c = 0; c < 4; c++) {
    const u16* in_c = XB + (size_t)c * 4096 * 1024;
    u16* out_c = FA + (size_t)c * 4096 * 1024;
    gemm_bt<1, 0><<<dim3(32, 32), blk, 0, stream>>>(in_c, WT1, bf1, FB, 4096,
                                                    4096, 1024);
    gemm_bt<0, 0><<<dim3(8, 32), blk, 0, stream>>>(FB, WT2, bf2, out_c, 4096,
                                                   1024, 4096);
  }
  ln_res<<<16384, blk, 0, stream>>>(FA, O2, g3, be3, O0, nullptr);  // out3

  // outputs 1 and 2 must be zeros
  hipMemsetAsync(O1, 0, 2 * S * 4, stream);
}

// Round 4
// 1048.768 us; speedup vs baseline: 1.2531x; 1.2531x over previous
//
#include <hip/hip_runtime.h>
#include <cstdint>

typedef unsigned short u16;
typedef __bf16 bf16x8 __attribute__((ext_vector_type(8)));
typedef float f32x4 __attribute__((ext_vector_type(4)));

__device__ __forceinline__ float bf2f(u16 h) {
  union { uint32_t u; float f; } v; v.u = (uint32_t)h << 16; return v.f;
}
__device__ __forceinline__ u16 f2bf(float f) {
  union { float f; uint32_t u; } v; v.f = f;
  uint32_t r = v.u + 0x7fffu + ((v.u >> 16) & 1u);
  return (u16)(r >> 16);
}
__device__ __forceinline__ float sigmoidf_(float x) {
  return 1.0f / (1.0f + __expf(-x));
}
__device__ __forceinline__ void load_lds16(const void* g, void* l) {
  __builtin_amdgcn_global_load_lds(
      (const __attribute__((address_space(1))) void*)g,
      (__attribute__((address_space(3))) void*)l, 16, 0, 0);
}

// ---------------- flat convert f32 -> bf16 (n multiple of 4) -------------
__global__ __launch_bounds__(256) void cvt_f2b(const float* __restrict__ in,
                                               u16* __restrict__ out) {
  long i = ((long)blockIdx.x * 256 + threadIdx.x) * 4;
  float4 v = *(const float4*)(in + i);
  uint2 o;
  o.x = (uint32_t)f2bf(v.x) | ((uint32_t)f2bf(v.y) << 16);
  o.y = (uint32_t)f2bf(v.z) | ((uint32_t)f2bf(v.w) << 16);
  *((uint2*)(out + i)) = o;
}

// ------------- transpose+convert: in f32 [K][N] -> out bf16 [N][K] -------
__global__ __launch_bounds__(256) void transpose_cvt(
    const float* __restrict__ in, u16* __restrict__ out, int K, int N) {
  __shared__ float t[32][33];
  int n0 = blockIdx.x * 32, k0 = blockIdx.y * 32;
  int tx = threadIdx.x & 31, ty = threadIdx.x >> 5;
#pragma unroll
  for (int i = 0; i < 32; i += 8)
    t[ty + i][tx] = in[(long)(k0 + ty + i) * N + n0 + tx];
  __syncthreads();
#pragma unroll
  for (int i = 0; i < 32; i += 8)
    out[(long)(n0 + ty + i) * K + k0 + tx] = f2bf(t[tx][ty + i]);
}

// ------ fused q,k projection from bf16: [T,1024]@[1024,16]x2 -> f32 ------
__global__ __launch_bounds__(256) void proj_qk_b(
    const u16* __restrict__ xb, const float* __restrict__ wq,
    const float* __restrict__ bq, const float* __restrict__ wk,
    const float* __restrict__ bk, float* __restrict__ qout,
    float* __restrict__ kout) {
  int tid = threadIdx.x;
  long t0 = (long)blockIdx.x * 16;
  int col = tid & 15, tok = tid >> 4;
  const u16* xr = xb + (t0 + tok) * 1024;
  float aq = 0.f, ak = 0.f;
  for (int k = 0; k < 1024; k += 4) {
    uint2 xv = *(const uint2*)(xr + k);
    float x0 = bf2f((u16)(xv.x & 0xffff)), x1 = bf2f((u16)(xv.x >> 16));
    float x2 = bf2f((u16)(xv.y & 0xffff)), x3 = bf2f((u16)(xv.y >> 16));
    aq += x0 * wq[(long)k * 16 + col] + x1 * wq[(long)(k + 1) * 16 + col] +
          x2 * wq[(long)(k + 2) * 16 + col] + x3 * wq[(long)(k + 3) * 16 + col];
    ak += x0 * wk[(long)k * 16 + col] + x1 * wk[(long)(k + 1) * 16 + col] +
          x2 * wk[(long)(k + 2) * 16 + col] + x3 * wk[(long)(k + 3) * 16 + col];
  }
  qout[(t0 + tok) * 16 + col] = aq + bq[col];
  kout[(t0 + tok) * 16 + col] = ak + bk[col];
}

// ------ single projection from bf16 ------
__global__ __launch_bounds__(256) void proj_b(const u16* __restrict__ xb,
                                              const float* __restrict__ w,
                                              const float* __restrict__ b,
                                              float* __restrict__ out) {
  int tid = threadIdx.x;
  long t0 = (long)blockIdx.x * 16;
  int col = tid & 15, tok = tid >> 4;
  const u16* xr = xb + (t0 + tok) * 1024;
  float acc = 0.f;
  for (int k = 0; k < 1024; k += 4) {
    uint2 xv = *(const uint2*)(xr + k);
    acc += bf2f((u16)(xv.x & 0xffff)) * w[(long)k * 16 + col] +
           bf2f((u16)(xv.x >> 16)) * w[(long)(k + 1) * 16 + col] +
           bf2f((u16)(xv.y & 0xffff)) * w[(long)(k + 2) * 16 + col] +
           bf2f((u16)(xv.y >> 16)) * w[(long)(k + 3) * 16 + col];
  }
  out[(t0 + tok) * 16 + col] = acc + b[col];
}

// ------ single projection from f32 ------
__global__ __launch_bounds__(256) void proj_f(const float* __restrict__ in,
                                              const float* __restrict__ w,
                                              const float* __restrict__ b,
                                              float* __restrict__ out) {
  int tid = threadIdx.x;
  long t0 = (long)blockIdx.x * 16;
  int col = tid & 15, tok = tid >> 4;
  const float* xr = in + (t0 + tok) * 1024;
  float acc = 0.f;
  for (int k = 0; k < 1024; k += 4) {
    float4 xv = *(const float4*)(xr + k);
    acc += xv.x * w[(long)k * 16 + col] + xv.y * w[(long)(k + 1) * 16 + col] +
           xv.z * w[(long)(k + 2) * 16 + col] + xv.w * w[(long)(k + 3) * 16 + col];
  }
  out[(t0 + tok) * 16 + col] = acc + b[col];
}

// -------- MFMA GEMM: C[M,N] = act(A[M,K]bf16 @ BT[N,K]^T + bias_f32) -----
// XCD-chunked swizzle (T1); grid total must be % 8 == 0 (guarded).
template <int ACT>
__global__ __launch_bounds__(256) void gemm_bt(
    const u16* __restrict__ A, const u16* __restrict__ BT,
    const float* __restrict__ bias, u16* __restrict__ C, int M, int N, int K) {
  __shared__ __attribute__((aligned(16))) u16 sA[2][128 * 32];
  __shared__ __attribute__((aligned(16))) u16 sB[2][128 * 32];
  const int tid = threadIdx.x;
  const int wave = tid >> 6, lane = tid & 63;

  int nwg = gridDim.x * gridDim.y;
  int orig = blockIdx.y * gridDim.x + blockIdx.x;
  int wg = (nwg & 7) ? orig : ((orig & 7) * (nwg >> 3) + (orig >> 3));
  const long bn = (long)(wg % gridDim.x) * 128;
  const long bm = (long)(wg / gridDim.x) * 128;

  const int wr = (wave >> 1) * 64, wc = (wave & 1) * 64;
  const int lrow = lane & 15, g = lane >> 4;

  f32x4 acc[4][4] = {};

  const int KT = K >> 5;
  auto stage = [&](int buf, int kt) {
    const u16* Ab = A + bm * K + (long)kt * 32;
    const u16* Bb = BT + bn * K + (long)kt * 32;
#pragma unroll
    for (int r = 0; r < 2; r++) {
      int slot0 = (r * 4 + wave) * 64;
      int slot = slot0 + lane;
      long row = slot >> 2;
      int kg = slot & 3;
      load_lds16(Ab + row * K + kg * 8, &sA[buf][slot0 * 8]);
      load_lds16(Bb + row * K + kg * 8, &sB[buf][slot0 * 8]);
    }
  };
  stage(0, 0);
  __syncthreads();
  for (int kt = 0; kt < KT; kt++) {
    int cur = kt & 1;
    if (kt + 1 < KT) stage(cur ^ 1, kt + 1);
    bf16x8 af[4], bfr[4];
#pragma unroll
    for (int m = 0; m < 4; m++)
      af[m] = *(const bf16x8*)&sA[cur][(wr + m * 16 + lrow) * 32 + g * 8];
#pragma unroll
    for (int n = 0; n < 4; n++)
      bfr[n] = *(const bf16x8*)&sB[cur][(wc + n * 16 + lrow) * 32 + g * 8];
#pragma unroll
    for (int m = 0; m < 4; m++)
#pragma unroll
      for (int n = 0; n < 4; n++)
        acc[m][n] = __builtin_amdgcn_mfma_f32_16x16x32_bf16(af[m], bfr[n],
                                                            acc[m][n], 0, 0, 0);
    __syncthreads();
  }
#pragma unroll
  for (int m = 0; m < 4; m++) {
#pragma unroll
    for (int n = 0; n < 4; n++) {
      long col = bn + wc + n * 16 + lrow;
      float bb = bias[col];
#pragma unroll
      for (int i = 0; i < 4; i++) {
        long row = bm + wr + m * 16 + g * 4 + i;
        float v = acc[m][n][i] + bb;
        if (ACT == 1) v = fmaxf(v, 0.f);
        C[row * N + col] = f2bf(v);
      }
    }
  }
}

// -- kv partial: part[b,h,sc,d] = sum_{s in chunk} sig(k)*v  (v bf16) -----
__global__ __launch_bounds__(256) void kv_part(const float* __restrict__ kp,
                                               const u16* __restrict__ v,
                                               float* __restrict__ part) {
  int bid = blockIdx.x;
  int sc = bid & 7, h = (bid >> 3) & 15, b = bid >> 7;
  int d = threadIdx.x & 63, si = threadIdx.x >> 6;
  float acc = 0.f;
  int s0 = sc * 512;
  for (int s = s0 + si; s < s0 + 512; s += 4) {
    long tok = (long)b * 4096 + s;
    float sk = sigmoidf_(kp[tok * 16 + h]);
    acc += sk * bf2f(v[tok * 1024 + h * 64 + d]);
  }
  __shared__ float red[4][64];
  red[si][d] = acc;
  __syncthreads();
  if (si == 0)
    part[(long)bid * 64 + d] = red[0][d] + red[1][d] + red[2][d] + red[3][d];
}

// ---------------- reduce chunks + cumsum over heads ----------------------
__global__ __launch_bounds__(64) void kv_finish(const float* __restrict__ part,
                                                float* __restrict__ scum) {
  int b = blockIdx.x, d = threadIdx.x;
  float run = 0.f;
  for (int h = 0; h < 16; h++) {
    float s = 0.f;
    for (int sc = 0; sc < 8; sc++)
      s += part[(((long)b * 16 + h) * 8 + sc) * 64 + d];
    run += s;
    scum[((long)b * 16 + h) * 64 + d] = run;
  }
}

// ------- pre[t, h*64+d] = sigmoid(q[t,h]) * scum[b,h,d]  -> bf16 ---------
__global__ __launch_bounds__(256) void premul(const float* __restrict__ qp,
                                              const float* __restrict__ scum,
                                              u16* __restrict__ out) {
  long idx = ((long)blockIdx.x * 256 + threadIdx.x) * 8;
  long tok = idx >> 10;
  int c = (int)(idx & 1023);
  int h = c >> 6, d0 = c & 63;
  int b = (int)(tok >> 12);
  float sq = sigmoidf_(qp[tok * 16 + h]);
  const float* sp = scum + ((long)b * 16 + h) * 64 + d0;
  uint4 o;
  o.x = (uint32_t)f2bf(sq * sp[0]) | ((uint32_t)f2bf(sq * sp[1]) << 16);
  o.y = (uint32_t)f2bf(sq * sp[2]) | ((uint32_t)f2bf(sq * sp[3]) << 16);
  o.z = (uint32_t)f2bf(sq * sp[4]) | ((uint32_t)f2bf(sq * sp[5]) << 16);
  o.w = (uint32_t)f2bf(sq * sp[6]) | ((uint32_t)f2bf(sq * sp[7]) << 16);
  *((uint4*)(out + idx)) = o;
}

// --- out_f32 = LayerNorm(a_bf16 + r_f32)*g + be ; optional bf16 copy -----
__global__ __launch_bounds__(256) void ln_res(const u16* __restrict__ a,
                                              const float* __restrict__ r,
                                              const float* __restrict__ g,
                                              const float* __restrict__ be,
                                              float* __restrict__ out,
                                              u16* __restrict__ outb) {
  long row = blockIdx.x;
  int tid = threadIdx.x;
  uint2 av = ((const uint2*)(a + row * 1024))[tid];
  float4 rv = ((const float4*)(r + row * 1024))[tid];
  float y[4];
  y[0] = bf2f((u16)(av.x & 0xffff)) + rv.x;
  y[1] = bf2f((u16)(av.x >> 16)) + rv.y;
  y[2] = bf2f((u16)(av.y & 0xffff)) + rv.z;
  y[3] = bf2f((u16)(av.y >> 16)) + rv.w;
  float s = y[0] + y[1] + y[2] + y[3];
  float q = y[0] * y[0] + y[1] * y[1] + y[2] * y[2] + y[3] * y[3];
#pragma unroll
  for (int o = 32; o > 0; o >>= 1) {
    s += __shfl_down(s, o);
    q += __shfl_down(q, o);
  }
  __shared__ float s1[4], s2[4];
  int wid = tid >> 6, lane = tid & 63;
  if (lane == 0) { s1[wid] = s; s2[wid] = q; }
  __syncthreads();
  s = s1[0] + s1[1] + s1[2] + s1[3];
  q = s2[0] + s2[1] + s2[2] + s2[3];
  float mu = s * (1.f / 1024.f);
  float var = q * (1.f / 1024.f) - mu * mu;
  float inv = rsqrtf(fmaxf(var, 0.f) + 1e-6f);
  float4 gv = ((const float4*)g)[tid], bv = ((const float4*)be)[tid];
  float o0 = gv.x * (y[0] - mu) * inv + bv.x;
  float o1 = gv.y * (y[1] - mu) * inv + bv.y;
  float o2 = gv.z * (y[2] - mu) * inv + bv.z;
  float o3 = gv.w * (y[3] - mu) * inv + bv.w;
  ((float4*)(out + row * 1024))[tid] = make_float4(o0, o1, o2, o3);
  if (outb != nullptr) {
    uint2 ob;
    ob.x = (uint32_t)f2bf(o0) | ((uint32_t)f2bf(o1) << 16);
    ob.y = (uint32_t)f2bf(o2) | ((uint32_t)f2bf(o3) << 16);
    ((uint2*)(outb + row * 1024))[tid] = ob;
  }
}

extern "C" void kernel_launch(void* const* d_in, const int* in_sizes, int n_in,
                              void* d_out, int out_size, void* d_ws,
                              size_t ws_size, hipStream_t stream) {
  const float* x   = (const float*)d_in[0];
  const float* enc = (const float*)d_in[1];
  const float* wq1 = (const float*)d_in[2];  const float* bq1 = (const float*)d_in[3];
  const float* wk1 = (const float*)d_in[4];  const float* bk1 = (const float*)d_in[5];
  const float* wv1 = (const float*)d_in[6];  const float* bv1 = (const float*)d_in[7];
  const float* wo1 = (const float*)d_in[8];  const float* bo1 = (const float*)d_in[9];
  const float* wq2 = (const float*)d_in[10]; const float* bq2 = (const float*)d_in[11];
  const float* wk2 = (const float*)d_in[12]; const float* bk2 = (const float*)d_in[13];
  const float* wv2 = (const float*)d_in[14]; const float* bv2 = (const float*)d_in[15];
  const float* wo2 = (const float*)d_in[16]; const float* bo2 = (const float*)d_in[17];
  const float* wf1 = (const float*)d_in[18]; const float* bf1 = (const float*)d_in[19];
  const float* wf2 = (const float*)d_in[20]; const float* bf2 = (const float*)d_in[21];
  const float* g1 = (const float*)d_in[22];  const float* be1 = (const float*)d_in[23];
  const float* g2 = (const float*)d_in[24];  const float* be2 = (const float*)d_in[25];
  const float* g3 = (const float*)d_in[26];  const float* be3 = (const float*)d_in[27];
  (void)in_sizes; (void)n_in; (void)out_size; (void)ws_size;

  const size_t S = (size_t)16384 * 1024;  // tokens * d_model
  float* O0 = (float*)d_out;              // out3

  char* base = (char*)d_ws;
  size_t off = 0;
  auto alloc = [&](size_t bytes) -> void* {
    void* p = base + off;
    off += (bytes + 255) & ~(size_t)255;
    return p;
  };
  u16* WT1   = (u16*)alloc((size_t)4096 * 1024 * 2);  // weight^T bf16
  u16* WT2   = (u16*)alloc((size_t)4096 * 1024 * 2);
  float* qb  = (float*)alloc((size_t)16384 * 16 * 4);
  float* kb  = (float*)alloc((size_t)16384 * 16 * 4);
  float* kvp = (float*)alloc((size_t)512 * 64 * 4);
  float* scm = (float*)alloc((size_t)4 * 16 * 64 * 4);
  u16* FA    = (u16*)alloc(S * 2);                    // bf16: v / attn / ffn_out
  u16* XB    = (u16*)alloc(S * 2);                    // bf16: x / enc / out2
  u16* FB    = (u16*)alloc(S * 2);                    // bf16: pre (attn input)
  u16* FM    = (u16*)alloc((size_t)16384 * 4096 * 2); // bf16: ffn mid (134MB)
  float* O1f = (float*)alloc(S * 4);                  // f32 out1
  float* O2f = (float*)alloc(S * 4);                  // f32 out2

  const int T = 16384;
  dim3 blk(256);

  // ---- MHA1 (q=k=v from x) ----
  cvt_f2b<<<16384, blk, 0, stream>>>(x, XB);
  transpose_cvt<<<dim3(32, 32), blk, 0, stream>>>(wv1, WT1, 1024, 1024);
  gemm_bt<0><<<dim3(8, 128), blk, 0, stream>>>(XB, WT1, bv1, FA, T, 1024, 1024);
  proj_qk_b<<<1024, blk, 0, stream>>>(XB, wq1, bq1, wk1, bk1, qb, kb);
  kv_part<<<512, blk, 0, stream>>>(kb, FA, kvp);
  kv_finish<<<4, 64, 0, stream>>>(kvp, scm);
  premul<<<8192, blk, 0, stream>>>(qb, scm, FB);
  transpose_cvt<<<dim3(32, 32), blk, 0, stream>>>(wo1, WT1, 1024, 1024);
  gemm_bt<0><<<dim3(8, 128), blk, 0, stream>>>(FB, WT1, bo1, FA, T, 1024, 1024);
  ln_res<<<16384, blk, 0, stream>>>(FA, x, g1, be1, O1f, nullptr);  // out1

  // ---- MHA2 (q from out1, k/v from enc) ----
  cvt_f2b<<<16384, blk, 0, stream>>>(enc, XB);
  transpose_cvt<<<dim3(32, 32), blk, 0, stream>>>(wv2, WT1, 1024, 1024);
  gemm_bt<0><<<dim3(8, 128), blk, 0, stream>>>(XB, WT1, bv2, FA, T, 1024, 1024);
  proj_f<<<1024, blk, 0, stream>>>(O1f, wq2, bq2, qb);
  proj_b<<<1024, blk, 0, stream>>>(XB, wk2, bk2, kb);
  kv_part<<<512, blk, 0, stream>>>(kb, FA, kvp);
  kv_finish<<<4, 64, 0, stream>>>(kvp, scm);
  premul<<<8192, blk, 0, stream>>>(qb, scm, FB);
  transpose_cvt<<<dim3(32, 32), blk, 0, stream>>>(wo2, WT1, 1024, 1024);
  gemm_bt<0><<<dim3(8, 128), blk, 0, stream>>>(FB, WT1, bo2, FA, T, 1024, 1024);
  ln_res<<<16384, blk, 0, stream>>>(FA, O1f, g2, be2, O2f, XB);  // out2 (+bf16)

  // ---- FFN (full-size, no chunking) ----
  transpose_cvt<<<dim3(128, 32), blk, 0, stream>>>(wf1, WT1, 1024, 4096);
  transpose_cvt<<<dim3(32, 128), blk, 0, stream>>>(wf2, WT2, 4096, 1024);
  gemm_bt<1><<<dim3(32, 128), blk, 0, stream>>>(XB, WT1, bf1, FM, T, 4096, 1024);
  gemm_bt<0><<<dim3(8, 128), blk, 0, stream>>>(FM, WT2, bf2, FA, T, 1024, 4096);
  ln_res<<<16384, blk, 0, stream>>>(FA, O2f, g3, be3, O0, nullptr);  // out3

  // outputs 1 and 2 must be zeros
  hipMemsetAsync((float*)d_out + S, 0, 2 * S * 4, stream);
}

// Round 5
// 948.776 us; speedup vs baseline: 1.3851x; 1.1054x over previous
//
#include <hip/hip_runtime.h>
#include <cstdint>

typedef unsigned short u16;
typedef __bf16 bf16x8 __attribute__((ext_vector_type(8)));
typedef float f32x4 __attribute__((ext_vector_type(4)));

__device__ __forceinline__ float bf2f(u16 h) {
  union { uint32_t u; float f; } v; v.u = (uint32_t)h << 16; return v.f;
}
__device__ __forceinline__ u16 f2bf(float f) {
  union { float f; uint32_t u; } v; v.f = f;
  uint32_t r = v.u + 0x7fffu + ((v.u >> 16) & 1u);
  return (u16)(r >> 16);
}
__device__ __forceinline__ float sigmoidf_(float x) {
  return 1.0f / (1.0f + __expf(-x));
}
__device__ __forceinline__ void load_lds16(const void* g, void* l) {
  __builtin_amdgcn_global_load_lds(
      (const __attribute__((address_space(1))) void*)g,
      (__attribute__((address_space(3))) void*)l, 16, 0, 0);
}
#define BAR() __builtin_amdgcn_s_barrier()
#define WAITLGKM() asm volatile("s_waitcnt lgkmcnt(0)" ::: "memory")
#define WAITVM4() asm volatile("s_waitcnt vmcnt(4)" ::: "memory")

// ---------------- flat convert f32 -> bf16 (n multiple of 4) -------------
__global__ __launch_bounds__(256) void cvt_f2b(const float* __restrict__ in,
                                               u16* __restrict__ out) {
  long i = ((long)blockIdx.x * 256 + threadIdx.x) * 4;
  float4 v = *(const float4*)(in + i);
  uint2 o;
  o.x = (uint32_t)f2bf(v.x) | ((uint32_t)f2bf(v.y) << 16);
  o.y = (uint32_t)f2bf(v.z) | ((uint32_t)f2bf(v.w) << 16);
  *((uint2*)(out + i)) = o;
}

// ------------- transpose+convert: in f32 [K][N] -> out bf16 [N][K] -------
__global__ __launch_bounds__(256) void transpose_cvt(
    const float* __restrict__ in, u16* __restrict__ out, int K, int N) {
  __shared__ float t[32][33];
  int n0 = blockIdx.x * 32, k0 = blockIdx.y * 32;
  int tx = threadIdx.x & 31, ty = threadIdx.x >> 5;
#pragma unroll
  for (int i = 0; i < 32; i += 8)
    t[ty + i][tx] = in[(long)(k0 + ty + i) * N + n0 + tx];
  __syncthreads();
#pragma unroll
  for (int i = 0; i < 32; i += 8)
    out[(long)(n0 + ty + i) * K + k0 + tx] = f2bf(t[tx][ty + i]);
}

// ------ fused q,k projection from bf16: [T,1024]@[1024,16]x2 -> f32 ------
__global__ __launch_bounds__(256) void proj_qk_b(
    const u16* __restrict__ xb, const float* __restrict__ wq,
    const float* __restrict__ bq, const float* __restrict__ wk,
    const float* __restrict__ bk, float* __restrict__ qout,
    float* __restrict__ kout) {
  int tid = threadIdx.x;
  long t0 = (long)blockIdx.x * 16;
  int col = tid & 15, tok = tid >> 4;
  const u16* xr = xb + (t0 + tok) * 1024;
  float aq = 0.f, ak = 0.f;
  for (int k = 0; k < 1024; k += 4) {
    uint2 xv = *(const uint2*)(xr + k);
    float x0 = bf2f((u16)(xv.x & 0xffff)), x1 = bf2f((u16)(xv.x >> 16));
    float x2 = bf2f((u16)(xv.y & 0xffff)), x3 = bf2f((u16)(xv.y >> 16));
    aq += x0 * wq[(long)k * 16 + col] + x1 * wq[(long)(k + 1) * 16 + col] +
          x2 * wq[(long)(k + 2) * 16 + col] + x3 * wq[(long)(k + 3) * 16 + col];
    ak += x0 * wk[(long)k * 16 + col] + x1 * wk[(long)(k + 1) * 16 + col] +
          x2 * wk[(long)(k + 2) * 16 + col] + x3 * wk[(long)(k + 3) * 16 + col];
  }
  qout[(t0 + tok) * 16 + col] = aq + bq[col];
  kout[(t0 + tok) * 16 + col] = ak + bk[col];
}

// ------ single projection from bf16 ------
__global__ __launch_bounds__(256) void proj_b(const u16* __restrict__ xb,
                                              const float* __restrict__ w,
                                              const float* __restrict__ b,
                                              float* __restrict__ out) {
  int tid = threadIdx.x;
  long t0 = (long)blockIdx.x * 16;
  int col = tid & 15, tok = tid >> 4;
  const u16* xr = xb + (t0 + tok) * 1024;
  float acc = 0.f;
  for (int k = 0; k < 1024; k += 4) {
    uint2 xv = *(const uint2*)(xr + k);
    acc += bf2f((u16)(xv.x & 0xffff)) * w[(long)k * 16 + col] +
           bf2f((u16)(xv.x >> 16)) * w[(long)(k + 1) * 16 + col] +
           bf2f((u16)(xv.y & 0xffff)) * w[(long)(k + 2) * 16 + col] +
           bf2f((u16)(xv.y >> 16)) * w[(long)(k + 3) * 16 + col];
  }
  out[(t0 + tok) * 16 + col] = acc + b[col];
}

// ------ single projection from f32 ------
__global__ __launch_bounds__(256) void proj_f(const float* __restrict__ in,
                                              const float* __restrict__ w,
                                              const float* __restrict__ b,
                                              float* __restrict__ out) {
  int tid = threadIdx.x;
  long t0 = (long)blockIdx.x * 16;
  int col = tid & 15, tok = tid >> 4;
  const float* xr = in + (t0 + tok) * 1024;
  float acc = 0.f;
  for (int k = 0; k < 1024; k += 4) {
    float4 xv = *(const float4*)(xr + k);
    acc += xv.x * w[(long)k * 16 + col] + xv.y * w[(long)(k + 1) * 16 + col] +
           xv.z * w[(long)(k + 2) * 16 + col] + xv.w * w[(long)(k + 3) * 16 + col];
  }
  out[(t0 + tok) * 16 + col] = acc + b[col];
}

// ===== 256x256 8-phase MFMA GEMM (T1+T2+T3+T4+T5) =========================
// C[M,N] = act(A[M,K]bf16 @ BT[N,K]^T + bias_f32), M%256==0, N%256==0,
// K%128==0. 512 threads = 8 waves (2M x 4N). LDS 128KB: 2 bufs x {A,B} x
// [kk(2)][row(256)][k(32)] bf16, st_16x32 swizzle (XOR k-bit4 with row-bit3)
// applied as: linear global_load_lds dest + inverse-swizzled global source,
// swizzled ds_read address.
template <int ACT>
__global__ __launch_bounds__(512) void gemm256(
    const u16* __restrict__ A, const u16* __restrict__ BT,
    const float* __restrict__ bias, u16* __restrict__ C, int M, int N,
    int K) {
  __shared__ __attribute__((aligned(16))) u16 lds[65536];  // 128 KB
  const int tid = threadIdx.x;
  const int wid = tid >> 6, lane = tid & 63;
  const int wm = wid >> 2, wn = wid & 3;
  const int lrow = lane & 15, g = lane >> 4;

  int nwg = gridDim.x * gridDim.y;
  int orig = blockIdx.y * gridDim.x + blockIdx.x;
  int wg = (nwg & 7) ? orig : ((orig & 7) * (nwg >> 3) + (orig >> 3));
  const long bn = (long)(wg % gridDim.x) * 256;
  const long bm = (long)(wg / gridDim.x) * 256;

  // staging addresses: chunk j covers region rows [j*128, j*128+128)
  const int rr = wid * 16 + (lane >> 2);                    // region row, j=0
  const int esrc = ((lane & 3) * 8) ^ (((lane >> 5) & 1) * 16);  // src swizzle
  const u16* Abase = A + (bm + rr) * (long)K + esrc;
  const u16* Bbase = BT + (bn + rr) * (long)K + esrc;
  const long jstep = (long)128 * K;
  char* ldsc = (char*)lds;
  const int ldsw = wid * 1024;

  // ds_read offsets (bytes) with read-side swizzle
  const int swr = ((lrow >> 3) & 1) * 32;
  int aoff[8], boff[4];
#pragma unroll
  for (int m = 0; m < 8; m++)
    aoff[m] = (wm * 128 + m * 16 + lrow) * 64 + ((g * 16) ^ swr);
#pragma unroll
  for (int n = 0; n < 4; n++)
    boff[n] = 32768 + (wn * 64 + n * 16 + lrow) * 64 + ((g * 16) ^ swr);

  f32x4 acc[8][4] = {};
  const int KT = K >> 6;  // 64-wide K-tiles; buf0 = even kt, buf1 = odd kt

  auto stage = [&](int arr, int buf, int kk, int kt) {
    if (kt >= KT) return;
    const u16* src = (arr ? Bbase : Abase) + (long)kt * 64 + kk * 32;
    int dst = buf * 65536 + arr * 32768 + kk * 16384 + ldsw;
    load_lds16(src, ldsc + dst);                  // rows 0-127
    load_lds16(src + jstep, ldsc + dst + 8192);   // rows 128-255
  };
  auto lda = [&](bf16x8* af, int buf, int kk) {
    const char* base = ldsc + buf * 65536 + kk * 16384;
#pragma unroll
    for (int m = 0; m < 8; m++) af[m] = *(const bf16x8*)(base + aoff[m]);
  };
  auto ldb = [&](bf16x8* bq, int buf, int kk, int nh) {
    const char* base = ldsc + buf * 65536 + kk * 16384;
    bq[0] = *(const bf16x8*)(base + boff[nh * 2]);
    bq[1] = *(const bf16x8*)(base + boff[nh * 2 + 1]);
  };
  auto mmaq = [&](const bf16x8* af, const bf16x8* bq, int nh) {
    __builtin_amdgcn_s_setprio(1);
#pragma unroll
    for (int m = 0; m < 8; m++) {
      acc[m][nh * 2] = __builtin_amdgcn_mfma_f32_16x16x32_bf16(
          af[m], bq[0], acc[m][nh * 2], 0, 0, 0);
      acc[m][nh * 2 + 1] = __builtin_amdgcn_mfma_f32_16x16x32_bf16(
          af[m], bq[1], acc[m][nh * 2 + 1], 0, 0, 0);
    }
    __builtin_amdgcn_s_setprio(0);
  };

  // prologue: kt0 fully + kt1.kk0 ; ensure buf0 landed (leave 4 in flight)
  stage(0, 0, 0, 0); stage(1, 0, 0, 0);
  stage(0, 0, 1, 0); stage(1, 0, 1, 0);
  stage(0, 1, 0, 1); stage(1, 1, 0, 1);
  WAITVM4();
  BAR();

  for (int kt = 0; kt < KT; kt += 2) {
    bf16x8 af[8], bq[2];
    // ph1: A(b0,kk0)+B(b0,kk0,nh0); stage A(kt+1).kk1
    lda(af, 0, 0); ldb(bq, 0, 0, 0);
    stage(0, 1, 1, kt + 1);
    BAR(); WAITLGKM();
    mmaq(af, bq, 0);
    BAR();
    // ph2: B(b0,kk0,nh1); stage B(kt+1).kk1
    ldb(bq, 0, 0, 1);
    stage(1, 1, 1, kt + 1);
    BAR(); WAITLGKM();
    mmaq(af, bq, 1);
    BAR();
    // ph3: A(b0,kk1)+B(b0,kk1,nh0); stage A(kt+2).kk0
    lda(af, 0, 1); ldb(bq, 0, 1, 0);
    stage(0, 0, 0, kt + 2);
    BAR(); WAITLGKM();
    mmaq(af, bq, 0);
    BAR();
    // ph4: B(b0,kk1,nh1); stage B(kt+2).kk0; vmcnt
    ldb(bq, 0, 1, 1);
    stage(1, 0, 0, kt + 2);
    WAITVM4();
    BAR(); WAITLGKM();
    mmaq(af, bq, 1);
    BAR();
    // ph5: A(b1,kk0)+B(b1,kk0,nh0); stage A(kt+2).kk1
    lda(af, 1, 0); ldb(bq, 1, 0, 0);
    stage(0, 0, 1, kt + 2);
    BAR(); WAITLGKM();
    mmaq(af, bq, 0);
    BAR();
    // ph6: B(b1,kk0,nh1); stage B(kt+2).kk1
    ldb(bq, 1, 0, 1);
    stage(1, 0, 1, kt + 2);
    BAR(); WAITLGKM();
    mmaq(af, bq, 1);
    BAR();
    // ph7: A(b1,kk1)+B(b1,kk1,nh0); stage A(kt+3).kk0
    lda(af, 1, 1); ldb(bq, 1, 1, 0);
    stage(0, 1, 0, kt + 3);
    BAR(); WAITLGKM();
    mmaq(af, bq, 0);
    BAR();
    // ph8: B(b1,kk1,nh1); stage B(kt+3).kk0; vmcnt
    ldb(bq, 1, 1, 1);
    stage(1, 1, 0, kt + 3);
    WAITVM4();
    BAR(); WAITLGKM();
    mmaq(af, bq, 1);
    BAR();
  }

#pragma unroll
  for (int n = 0; n < 4; n++) {
    long col = bn + wn * 64 + n * 16 + lrow;
    float bb = bias[col];
#pragma unroll
    for (int m = 0; m < 8; m++) {
#pragma unroll
      for (int i = 0; i < 4; i++) {
        long row = bm + wm * 128 + m * 16 + g * 4 + i;
        float v = acc[m][n][i] + bb;
        if (ACT == 1) v = fmaxf(v, 0.f);
        C[row * N + col] = f2bf(v);
      }
    }
  }
}

// ---- (fallback, uninstantiated) 128x128 2-phase GEMM ----
template <int ACT>
__global__ __launch_bounds__(256) void gemm_bt(
    const u16* __restrict__ A, const u16* __restrict__ BT,
    const float* __restrict__ bias, u16* __restrict__ C, int M, int N, int K) {
  __shared__ __attribute__((aligned(16))) u16 sA[2][128 * 32];
  __shared__ __attribute__((aligned(16))) u16 sB[2][128 * 32];
  const int tid = threadIdx.x;
  const int wave = tid >> 6, lane = tid & 63;
  int nwg = gridDim.x * gridDim.y;
  int orig = blockIdx.y * gridDim.x + blockIdx.x;
  int wg = (nwg & 7) ? orig : ((orig & 7) * (nwg >> 3) + (orig >> 3));
  const long bn = (long)(wg % gridDim.x) * 128;
  const long bm = (long)(wg / gridDim.x) * 128;
  const int wr = (wave >> 1) * 64, wc = (wave & 1) * 64;
  const int lrow = lane & 15, g = lane >> 4;
  f32x4 acc[4][4] = {};
  const int KT = K >> 5;
  auto stage = [&](int buf, int kt) {
    const u16* Ab = A + bm * K + (long)kt * 32;
    const u16* Bb = BT + bn * K + (long)kt * 32;
#pragma unroll
    for (int r = 0; r < 2; r++) {
      int slot0 = (r * 4 + wave) * 64;
      int slot = slot0 + lane;
      long row = slot >> 2;
      int kg = slot & 3;
      load_lds16(Ab + row * K + kg * 8, &sA[buf][slot0 * 8]);
      load_lds16(Bb + row * K + kg * 8, &sB[buf][slot0 * 8]);
    }
  };
  stage(0, 0);
  __syncthreads();
  for (int kt = 0; kt < KT; kt++) {
    int cur = kt & 1;
    if (kt + 1 < KT) stage(cur ^ 1, kt + 1);
    bf16x8 af[4], bfr[4];
#pragma unroll
    for (int m = 0; m < 4; m++)
      af[m] = *(const bf16x8*)&sA[cur][(wr + m * 16 + lrow) * 32 + g * 8];
#pragma unroll
    for (int n = 0; n < 4; n++)
      bfr[n] = *(const bf16x8*)&sB[cur][(wc + n * 16 + lrow) * 32 + g * 8];
#pragma unroll
    for (int m = 0; m < 4; m++)
#pragma unroll
      for (int n = 0; n < 4; n++)
        acc[m][n] = __builtin_amdgcn_mfma_f32_16x16x32_bf16(af[m], bfr[n],
                                                            acc[m][n], 0, 0, 0);
    __syncthreads();
  }
#pragma unroll
  for (int m = 0; m < 4; m++)
#pragma unroll
    for (int n = 0; n < 4; n++) {
      long col = bn + wc + n * 16 + lrow;
      float bb = bias[col];
#pragma unroll
      for (int i = 0; i < 4; i++) {
        long row = bm + wr + m * 16 + g * 4 + i;
        float v = acc[m][n][i] + bb;
        if (ACT == 1) v = fmaxf(v, 0.f);
        C[row * N + col] = f2bf(v);
      }
    }
}

// -- kv partial: part[b,h,sc,d] = sum_{s in chunk} sig(k)*v  (v bf16) -----
__global__ __launch_bounds__(256) void kv_part(const float* __restrict__ kp,
                                               const u16* __restrict__ v,
                                               float* __restrict__ part) {
  int bid = blockIdx.x;
  int sc = bid & 7, h = (bid >> 3) & 15, b = bid >> 7;
  int d = threadIdx.x & 63, si = threadIdx.x >> 6;
  float acc = 0.f;
  int s0 = sc * 512;
  for (int s = s0 + si; s < s0 + 512; s += 4) {
    long tok = (long)b * 4096 + s;
    float sk = sigmoidf_(kp[tok * 16 + h]);
    acc += sk * bf2f(v[tok * 1024 + h * 64 + d]);
  }
  __shared__ float red[4][64];
  red[si][d] = acc;
  __syncthreads();
  if (si == 0)
    part[(long)bid * 64 + d] = red[0][d] + red[1][d] + red[2][d] + red[3][d];
}

// ---------------- reduce chunks + cumsum over heads ----------------------
__global__ __launch_bounds__(64) void kv_finish(const float* __restrict__ part,
                                                float* __restrict__ scum) {
  int b = blockIdx.x, d = threadIdx.x;
  float run = 0.f;
  for (int h = 0; h < 16; h++) {
    float s = 0.f;
    for (int sc = 0; sc < 8; sc++)
      s += part[(((long)b * 16 + h) * 8 + sc) * 64 + d];
    run += s;
    scum[((long)b * 16 + h) * 64 + d] = run;
  }
}

// ------- pre[t, h*64+d] = sigmoid(q[t,h]) * scum[b,h,d]  -> bf16 ---------
__global__ __launch_bounds__(256) void premul(const float* __restrict__ qp,
                                              const float* __restrict__ scum,
                                              u16* __restrict__ out) {
  long idx = ((long)blockIdx.x * 256 + threadIdx.x) * 8;
  long tok = idx >> 10;
  int c = (int)(idx & 1023);
  int h = c >> 6, d0 = c & 63;
  int b = (int)(tok >> 12);
  float sq = sigmoidf_(qp[tok * 16 + h]);
  const float* sp = scum + ((long)b * 16 + h) * 64 + d0;
  uint4 o;
  o.x = (uint32_t)f2bf(sq * sp[0]) | ((uint32_t)f2bf(sq * sp[1]) << 16);
  o.y = (uint32_t)f2bf(sq * sp[2]) | ((uint32_t)f2bf(sq * sp[3]) << 16);
  o.z = (uint32_t)f2bf(sq * sp[4]) | ((uint32_t)f2bf(sq * sp[5]) << 16);
  o.w = (uint32_t)f2bf(sq * sp[6]) | ((uint32_t)f2bf(sq * sp[7]) << 16);
  *((uint4*)(out + idx)) = o;
}

// --- out_f32 = LayerNorm(a_bf16 + r_f32)*g + be ; optional bf16 copy -----
__global__ __launch_bounds__(256) void ln_res(const u16* __restrict__ a,
                                              const float* __restrict__ r,
                                              const float* __restrict__ g,
                                              const float* __restrict__ be,
                                              float* __restrict__ out,
                                              u16* __restrict__ outb) {
  long row = blockIdx.x;
  int tid = threadIdx.x;
  uint2 av = ((const uint2*)(a + row * 1024))[tid];
  float4 rv = ((const float4*)(r + row * 1024))[tid];
  float y[4];
  y[0] = bf2f((u16)(av.x & 0xffff)) + rv.x;
  y[1] = bf2f((u16)(av.x >> 16)) + rv.y;
  y[2] = bf2f((u16)(av.y & 0xffff)) + rv.z;
  y[3] = bf2f((u16)(av.y >> 16)) + rv.w;
  float s = y[0] + y[1] + y[2] + y[3];
  float q = y[0] * y[0] + y[1] * y[1] + y[2] * y[2] + y[3] * y[3];
#pragma unroll
  for (int o = 32; o > 0; o >>= 1) {
    s += __shfl_down(s, o);
    q += __shfl_down(q, o);
  }
  __shared__ float s1[4], s2[4];
  int wid = tid >> 6, lane = tid & 63;
  if (lane == 0) { s1[wid] = s; s2[wid] = q; }
  __syncthreads();
  s = s1[0] + s1[1] + s1[2] + s1[3];
  q = s2[0] + s2[1] + s2[2] + s2[3];
  float mu = s * (1.f / 1024.f);
  float var = q * (1.f / 1024.f) - mu * mu;
  float inv = rsqrtf(fmaxf(var, 0.f) + 1e-6f);
  float4 gv = ((const float4*)g)[tid], bv = ((const float4*)be)[tid];
  float o0 = gv.x * (y[0] - mu) * inv + bv.x;
  float o1 = gv.y * (y[1] - mu) * inv + bv.y;
  float o2 = gv.z * (y[2] - mu) * inv + bv.z;
  float o3 = gv.w * (y[3] - mu) * inv + bv.w;
  ((float4*)(out + row * 1024))[tid] = make_float4(o0, o1, o2, o3);
  if (outb != nullptr) {
    uint2 ob;
    ob.x = (uint32_t)f2bf(o0) | ((uint32_t)f2bf(o1) << 16);
    ob.y = (uint32_t)f2bf(o2) | ((uint32_t)f2bf(o3) << 16);
    ((uint2*)(outb + row * 1024))[tid] = ob;
  }
}

extern "C" void kernel_launch(void* const* d_in, const int* in_sizes, int n_in,
                              void* d_out, int out_size, void* d_ws,
                              size_t ws_size, hipStream_t stream) {
  const float* x   = (const float*)d_in[0];
  const float* enc = (const float*)d_in[1];
  const float* wq1 = (const float*)d_in[2];  const float* bq1 = (const float*)d_in[3];
  const float* wk1 = (const float*)d_in[4];  const float* bk1 = (const float*)d_in[5];
  const float* wv1 = (const float*)d_in[6];  const float* bv1 = (const float*)d_in[7];
  const float* wo1 = (const float*)d_in[8];  const float* bo1 = (const float*)d_in[9];
  const float* wq2 = (const float*)d_in[10]; const float* bq2 = (const float*)d_in[11];
  const float* wk2 = (const float*)d_in[12]; const float* bk2 = (const float*)d_in[13];
  const float* wv2 = (const float*)d_in[14]; const float* bv2 = (const float*)d_in[15];
  const float* wo2 = (const float*)d_in[16]; const float* bo2 = (const float*)d_in[17];
  const float* wf1 = (const float*)d_in[18]; const float* bf1 = (const float*)d_in[19];
  const float* wf2 = (const float*)d_in[20]; const float* bf2 = (const float*)d_in[21];
  const float* g1 = (const float*)d_in[22];  const float* be1 = (const float*)d_in[23];
  const float* g2 = (const float*)d_in[24];  const float* be2 = (const float*)d_in[25];
  const float* g3 = (const float*)d_in[26];  const float* be3 = (const float*)d_in[27];
  (void)in_sizes; (void)n_in; (void)out_size; (void)ws_size;

  const size_t S = (size_t)16384 * 1024;  // tokens * d_model
  float* O0 = (float*)d_out;              // out3

  char* base = (char*)d_ws;
  size_t off = 0;
  auto alloc = [&](size_t bytes) -> void* {
    void* p = base + off;
    off += (bytes + 255) & ~(size_t)255;
    return p;
  };
  u16* WT1   = (u16*)alloc((size_t)4096 * 1024 * 2);  // weight^T bf16
  u16* WT2   = (u16*)alloc((size_t)4096 * 1024 * 2);
  float* qb  = (float*)alloc((size_t)16384 * 16 * 4);
  float* kb  = (float*)alloc((size_t)16384 * 16 * 4);
  float* kvp = (float*)alloc((size_t)512 * 64 * 4);
  float* scm = (float*)alloc((size_t)4 * 16 * 64 * 4);
  u16* FA    = (u16*)alloc(S * 2);                    // bf16: v / attn / ffn_out
  u16* XB    = (u16*)alloc(S * 2);                    // bf16: x / enc / out2
  u16* FB    = (u16*)alloc(S * 2);                    // bf16: pre (attn input)
  u16* FM    = (u16*)alloc((size_t)16384 * 4096 * 2); // bf16: ffn mid (134MB)
  float* O1f = (float*)alloc(S * 4);                  // f32 out1
  float* O2f = (float*)alloc(S * 4);                  // f32 out2

  const int T = 16384;
  dim3 blk(256), gblk(512);

  // ---- MHA1 (q=k=v from x) ----
  cvt_f2b<<<16384, blk, 0, stream>>>(x, XB);
  transpose_cvt<<<dim3(32, 32), blk, 0, stream>>>(wv1, WT1, 1024, 1024);
  gemm256<0><<<dim3(4, 64), gblk, 0, stream>>>(XB, WT1, bv1, FA, T, 1024, 1024);
  proj_qk_b<<<1024, blk, 0, stream>>>(XB, wq1, bq1, wk1, bk1, qb, kb);
  kv_part<<<512, blk, 0, stream>>>(kb, FA, kvp);
  kv_finish<<<4, 64, 0, stream>>>(kvp, scm);
  premul<<<8192, blk, 0, stream>>>(qb, scm, FB);
  transpose_cvt<<<dim3(32, 32), blk, 0, stream>>>(wo1, WT1, 1024, 1024);
  gemm256<0><<<dim3(4, 64), gblk, 0, stream>>>(FB, WT1, bo1, FA, T, 1024, 1024);
  ln_res<<<16384, blk, 0, stream>>>(FA, x, g1, be1, O1f, nullptr);  // out1

  // ---- MHA2 (q from out1, k/v from enc) ----
  cvt_f2b<<<16384, blk, 0, stream>>>(enc, XB);
  transpose_cvt<<<dim3(32, 32), blk, 0, stream>>>(wv2, WT1, 1024, 1024);
  gemm256<0><<<dim3(4, 64), gblk, 0, stream>>>(XB, WT1, bv2, FA, T, 1024, 1024);
  proj_f<<<1024, blk, 0, stream>>>(O1f, wq2, bq2, qb);
  proj_b<<<1024, blk, 0, stream>>>(XB, wk2, bk2, kb);
  kv_part<<<512, blk, 0, stream>>>(kb, FA, kvp);
  kv_finish<<<4, 64, 0, stream>>>(kvp, scm);
  premul<<<8192, blk, 0, stream>>>(qb, scm, FB);
  transpose_cvt<<<dim3(32, 32), blk, 0, stream>>>(wo2, WT1, 1024, 1024);
  gemm256<0><<<dim3(4, 64), gblk, 0, stream>>>(FB, WT1, bo2, FA, T, 1024, 1024);
  ln_res<<<16384, blk, 0, stream>>>(FA, O1f, g2, be2, O2f, XB);  // out2 (+bf16)

  // ---- FFN ----
  transpose_cvt<<<dim3(128, 32), blk, 0, stream>>>(wf1, WT1, 1024, 4096);
  transpose_cvt<<<dim3(32, 128), blk, 0, stream>>>(wf2, WT2, 4096, 1024);
  gemm256<1><<<dim3(16, 64), gblk, 0, stream>>>(XB, WT1, bf1, FM, T, 4096, 1024);
  gemm256<0><<<dim3(4, 64), gblk, 0, stream>>>(FM, WT2, bf2, FA, T, 1024, 4096);
  ln_res<<<16384, blk, 0, stream>>>(FA, O2f, g3, be3, O0, nullptr);  // out3

  // outputs 1 and 2 must be zeros
  hipMemsetAsync((float*)d_out + S, 0, 2 * S * 4, stream);
}

// Round 6
// 906.358 us; speedup vs baseline: 1.4499x; 1.0468x over previous
//
#include <hip/hip_runtime.h>
#include <cstdint>

typedef unsigned short u16;
typedef __bf16 bf16x8 __attribute__((ext_vector_type(8)));
typedef float f32x4 __attribute__((ext_vector_type(4)));

__device__ __forceinline__ float bf2f(u16 h) {
  union { uint32_t u; float f; } v; v.u = (uint32_t)h << 16; return v.f;
}
__device__ __forceinline__ u16 f2bf(float f) {
  union { float f; uint32_t u; } v; v.f = f;
  uint32_t r = v.u + 0x7fffu + ((v.u >> 16) & 1u);
  return (u16)(r >> 16);
}
__device__ __forceinline__ float sigmoidf_(float x) {
  return 1.0f / (1.0f + __expf(-x));
}
__device__ __forceinline__ void load_lds16(const void* g, void* l) {
  __builtin_amdgcn_global_load_lds(
      (const __attribute__((address_space(1))) void*)g,
      (__attribute__((address_space(3))) void*)l, 16, 0, 0);
}
#define BAR() __builtin_amdgcn_s_barrier()
#define WAITLGKM() asm volatile("s_waitcnt lgkmcnt(0)" ::: "memory")
#define WAITVM8() asm volatile("s_waitcnt vmcnt(8)" ::: "memory")
#define WAITVM4() asm volatile("s_waitcnt vmcnt(4)" ::: "memory")
#define WAITVM0() asm volatile("s_waitcnt vmcnt(0)" ::: "memory")

// ---------------- flat convert f32 -> bf16 (n multiple of 4) -------------
__global__ __launch_bounds__(256) void cvt_f2b(const float* __restrict__ in,
                                               u16* __restrict__ out) {
  long i = ((long)blockIdx.x * 256 + threadIdx.x) * 4;
  float4 v = *(const float4*)(in + i);
  uint2 o;
  o.x = (uint32_t)f2bf(v.x) | ((uint32_t)f2bf(v.y) << 16);
  o.y = (uint32_t)f2bf(v.z) | ((uint32_t)f2bf(v.w) << 16);
  *((uint2*)(out + i)) = o;
}

// ------------- transpose+convert: in f32 [K][N] -> out bf16 [N][K] -------
__global__ __launch_bounds__(256) void transpose_cvt(
    const float* __restrict__ in, u16* __restrict__ out, int K, int N) {
  __shared__ float t[32][33];
  int n0 = blockIdx.x * 32, k0 = blockIdx.y * 32;
  int tx = threadIdx.x & 31, ty = threadIdx.x >> 5;
#pragma unroll
  for (int i = 0; i < 32; i += 8)
    t[ty + i][tx] = in[(long)(k0 + ty + i) * N + n0 + tx];
  __syncthreads();
#pragma unroll
  for (int i = 0; i < 32; i += 8)
    out[(long)(n0 + ty + i) * K + k0 + tx] = f2bf(t[tx][ty + i]);
}

// ------ fused q,k projection from bf16: [T,1024]@[1024,16]x2 -> f32 ------
__global__ __launch_bounds__(256) void proj_qk_b(
    const u16* __restrict__ xb, const float* __restrict__ wq,
    const float* __restrict__ bq, const float* __restrict__ wk,
    const float* __restrict__ bk, float* __restrict__ qout,
    float* __restrict__ kout) {
  int tid = threadIdx.x;
  long t0 = (long)blockIdx.x * 16;
  int col = tid & 15, tok = tid >> 4;
  const u16* xr = xb + (t0 + tok) * 1024;
  float aq = 0.f, ak = 0.f;
  for (int k = 0; k < 1024; k += 4) {
    uint2 xv = *(const uint2*)(xr + k);
    float x0 = bf2f((u16)(xv.x & 0xffff)), x1 = bf2f((u16)(xv.x >> 16));
    float x2 = bf2f((u16)(xv.y & 0xffff)), x3 = bf2f((u16)(xv.y >> 16));
    aq += x0 * wq[(long)k * 16 + col] + x1 * wq[(long)(k + 1) * 16 + col] +
          x2 * wq[(long)(k + 2) * 16 + col] + x3 * wq[(long)(k + 3) * 16 + col];
    ak += x0 * wk[(long)k * 16 + col] + x1 * wk[(long)(k + 1) * 16 + col] +
          x2 * wk[(long)(k + 2) * 16 + col] + x3 * wk[(long)(k + 3) * 16 + col];
  }
  qout[(t0 + tok) * 16 + col] = aq + bq[col];
  kout[(t0 + tok) * 16 + col] = ak + bk[col];
}

// ------ single projection from bf16 ------
__global__ __launch_bounds__(256) void proj_b(const u16* __restrict__ xb,
                                              const float* __restrict__ w,
                                              const float* __restrict__ b,
                                              float* __restrict__ out) {
  int tid = threadIdx.x;
  long t0 = (long)blockIdx.x * 16;
  int col = tid & 15, tok = tid >> 4;
  const u16* xr = xb + (t0 + tok) * 1024;
  float acc = 0.f;
  for (int k = 0; k < 1024; k += 4) {
    uint2 xv = *(const uint2*)(xr + k);
    acc += bf2f((u16)(xv.x & 0xffff)) * w[(long)k * 16 + col] +
           bf2f((u16)(xv.x >> 16)) * w[(long)(k + 1) * 16 + col] +
           bf2f((u16)(xv.y & 0xffff)) * w[(long)(k + 2) * 16 + col] +
           bf2f((u16)(xv.y >> 16)) * w[(long)(k + 3) * 16 + col];
  }
  out[(t0 + tok) * 16 + col] = acc + b[col];
}

// ------ single projection from f32 ------
__global__ __launch_bounds__(256) void proj_f(const float* __restrict__ in,
                                              const float* __restrict__ w,
                                              const float* __restrict__ b,
                                              float* __restrict__ out) {
  int tid = threadIdx.x;
  long t0 = (long)blockIdx.x * 16;
  int col = tid & 15, tok = tid >> 4;
  const float* xr = in + (t0 + tok) * 1024;
  float acc = 0.f;
  for (int k = 0; k < 1024; k += 4) {
    float4 xv = *(const float4*)(xr + k);
    acc += xv.x * w[(long)k * 16 + col] + xv.y * w[(long)(k + 1) * 16 + col] +
           xv.z * w[(long)(k + 2) * 16 + col] + xv.w * w[(long)(k + 3) * 16 + col];
  }
  out[(t0 + tok) * 16 + col] = acc + b[col];
}

// ===== 256x256 4-phase MFMA GEMM (T1+T2+T3+T4+T5, coarse phases) ==========
// C[M,N] = act(A[M,K]bf16 @ BT[N,K]^T + bias), M%256==0, N%256==0, K%128==0.
// 512 threads = 8 waves (2M x 4N). LDS 128KB: [buf(2)][arr(2)][kk(2)][256][32]
// bf16, st-swizzle via inverse-swizzled global source + swizzled ds_read.
// Phase = {12 ds_read_b128; 4-load stage slot; vmcnt(8); bar; lgkm0;
// 32 MFMA (setprio); bar}. Stage slot (buf,kk) rotation: phA->B1.kk1(kt+1),
// phB->B0.kk0(kt+2), phC->B0.kk1(kt+2), phD->B1.kk0(kt+3); every read
// targets the slot staged 3 phases earlier, drained by the previous phase's
// vmcnt(8). Tail iteration peeled with vm(8)/vm(4)/vm(0). Epilogue staged
// through LDS for fully coalesced uint4 stores.
template <int ACT>
__global__ __launch_bounds__(512) void gemm256(
    const u16* __restrict__ A, const u16* __restrict__ BT,
    const float* __restrict__ bias, u16* __restrict__ C, int M, int N,
    int K) {
  __shared__ __attribute__((aligned(16))) u16 lds[65536];  // 128 KB
  const int tid = threadIdx.x;
  const int wid = tid >> 6, lane = tid & 63;
  const int wm = wid >> 2, wn = wid & 3;
  const int lrow = lane & 15, g = lane >> 4;

  int nwg = gridDim.x * gridDim.y;
  int orig = blockIdx.y * gridDim.x + blockIdx.x;
  int wg = (nwg & 7) ? orig : ((orig & 7) * (nwg >> 3) + (orig >> 3));
  const long bn = (long)(wg % gridDim.x) * 256;
  const long bm = (long)(wg / gridDim.x) * 256;

  const int rr = wid * 16 + (lane >> 2);                        // staging row
  const int esrc = ((lane & 3) * 8) ^ (((lane >> 5) & 1) * 16); // src swizzle
  const u16* Abase = A + (bm + rr) * (long)K + esrc;
  const u16* Bbase = BT + (bn + rr) * (long)K + esrc;
  const long jstep = (long)128 * K;
  char* ldsc = (char*)lds;
  const int ldsw = wid * 1024;

  const int swr = ((lrow >> 3) & 1) * 32;
  int aoff[8], boff[4];
#pragma unroll
  for (int m = 0; m < 8; m++)
    aoff[m] = (wm * 128 + m * 16 + lrow) * 64 + ((g * 16) ^ swr);
#pragma unroll
  for (int n = 0; n < 4; n++)
    boff[n] = 32768 + (wn * 64 + n * 16 + lrow) * 64 + ((g * 16) ^ swr);

  f32x4 acc[8][4] = {};
  const int KT = K >> 6;  // 64-wide K-tiles (even); buf = kt & 1

  // stage slot: A and B of (buf,kk) for K-tile kt  -> 4 global_load_lds
  auto stage = [&](int buf, int kk, int kt) {
    const u16* sA = Abase + (long)kt * 64 + kk * 32;
    const u16* sB = Bbase + (long)kt * 64 + kk * 32;
    int dA = buf * 65536 + kk * 16384 + ldsw;
    int dB = dA + 32768;
    load_lds16(sA, ldsc + dA);
    load_lds16(sA + jstep, ldsc + dA + 8192);
    load_lds16(sB, ldsc + dB);
    load_lds16(sB + jstep, ldsc + dB + 8192);
  };
  auto ldab = [&](bf16x8* af, bf16x8* bq, int buf, int kk) {
    const char* base = ldsc + buf * 65536 + kk * 16384;
#pragma unroll
    for (int m = 0; m < 8; m++) af[m] = *(const bf16x8*)(base + aoff[m]);
#pragma unroll
    for (int n = 0; n < 4; n++) bq[n] = *(const bf16x8*)(base + boff[n]);
  };
  auto mma32 = [&](const bf16x8* af, const bf16x8* bq) {
    __builtin_amdgcn_s_setprio(1);
#pragma unroll
    for (int m = 0; m < 8; m++)
#pragma unroll
      for (int n = 0; n < 4; n++)
        acc[m][n] = __builtin_amdgcn_mfma_f32_16x16x32_bf16(af[m], bq[n],
                                                            acc[m][n], 0, 0, 0);
    __builtin_amdgcn_s_setprio(0);
  };

  // prologue: S1=buf0.kk0(0) [phA], S2=buf0.kk1(0) [phB], S3=buf1.kk0(1) [phC]
  stage(0, 0, 0);
  stage(0, 1, 0);
  stage(1, 0, 1);
  WAITVM8();  // S1 landed
  BAR();

  bf16x8 af[8], bq[4];
  for (int kt = 0; kt + 3 < KT; kt += 2) {
    // phA: read buf0.kk0(kt); stage buf1.kk1(kt+1)
    ldab(af, bq, 0, 0);
    stage(1, 1, kt + 1);
    WAITVM8();
    BAR(); WAITLGKM();
    mma32(af, bq);
    BAR();
    // phB: read buf0.kk1(kt); stage buf0.kk0(kt+2)
    ldab(af, bq, 0, 1);
    stage(0, 0, kt + 2);
    WAITVM8();
    BAR(); WAITLGKM();
    mma32(af, bq);
    BAR();
    // phC: read buf1.kk0(kt+1); stage buf0.kk1(kt+2)
    ldab(af, bq, 1, 0);
    stage(0, 1, kt + 2);
    WAITVM8();
    BAR(); WAITLGKM();
    mma32(af, bq);
    BAR();
    // phD: read buf1.kk1(kt+1); stage buf1.kk0(kt+3)
    ldab(af, bq, 1, 1);
    stage(1, 0, kt + 3);
    WAITVM8();
    BAR(); WAITLGKM();
    mma32(af, bq);
    BAR();
  }
  {
    // peeled tail (kt = KT-2): exact vm drains with no further staging
    ldab(af, bq, 0, 0);
    stage(1, 1, KT - 1);
    WAITVM8();
    BAR(); WAITLGKM();
    mma32(af, bq);
    BAR();
    ldab(af, bq, 0, 1);
    WAITVM4();
    BAR(); WAITLGKM();
    mma32(af, bq);
    BAR();
    ldab(af, bq, 1, 0);
    WAITVM0();
    BAR(); WAITLGKM();
    mma32(af, bq);
    BAR();
    ldab(af, bq, 1, 1);
    BAR(); WAITLGKM();
    mma32(af, bq);
    BAR();
  }

  // ---- epilogue: bias/act -> LDS (bf16 tile) -> coalesced uint4 stores ----
#pragma unroll
  for (int n = 0; n < 4; n++) {
    int cl = wn * 64 + n * 16 + lrow;
    float bb = bias[bn + cl];
#pragma unroll
    for (int m = 0; m < 8; m++) {
      int rl = wm * 128 + m * 16 + g * 4;
#pragma unroll
      for (int i = 0; i < 4; i++) {
        float v = acc[m][n][i] + bb;
        if (ACT == 1) v = fmaxf(v, 0.f);
        lds[(rl + i) * 256 + cl] = f2bf(v);
      }
    }
  }
  BAR();
  const uint4* lv = (const uint4*)lds;
#pragma unroll
  for (int it = 0; it < 16; it++) {
    int idx = it * 512 + tid;          // 8192 uint4 total
    int row = idx >> 5;                // 32 uint4 per 256-col row
    int cu = (idx & 31) * 8;           // starting u16 col
    *(uint4*)&C[(bm + row) * (long)N + bn + cu] = lv[idx];
  }
}

// -- kv partial: part[b,h,sc,d] = sum_{s in chunk} sig(k)*v  (v bf16) -----
__global__ __launch_bounds__(256) void kv_part(const float* __restrict__ kp,
                                               const u16* __restrict__ v,
                                               float* __restrict__ part) {
  int bid = blockIdx.x;
  int sc = bid & 7, h = (bid >> 3) & 15, b = bid >> 7;
  int d = threadIdx.x & 63, si = threadIdx.x >> 6;
  float acc = 0.f;
  int s0 = sc * 512;
  for (int s = s0 + si; s < s0 + 512; s += 4) {
    long tok = (long)b * 4096 + s;
    float sk = sigmoidf_(kp[tok * 16 + h]);
    acc += sk * bf2f(v[tok * 1024 + h * 64 + d]);
  }
  __shared__ float red[4][64];
  red[si][d] = acc;
  __syncthreads();
  if (si == 0)
    part[(long)bid * 64 + d] = red[0][d] + red[1][d] + red[2][d] + red[3][d];
}

// ---------------- reduce chunks + cumsum over heads ----------------------
__global__ __launch_bounds__(64) void kv_finish(const float* __restrict__ part,
                                                float* __restrict__ scum) {
  int b = blockIdx.x, d = threadIdx.x;
  float run = 0.f;
  for (int h = 0; h < 16; h++) {
    float s = 0.f;
    for (int sc = 0; sc < 8; sc++)
      s += part[(((long)b * 16 + h) * 8 + sc) * 64 + d];
    run += s;
    scum[((long)b * 16 + h) * 64 + d] = run;
  }
}

// ------- pre[t, h*64+d] = sigmoid(q[t,h]) * scum[b,h,d]  -> bf16 ---------
__global__ __launch_bounds__(256) void premul(const float* __restrict__ qp,
                                              const float* __restrict__ scum,
                                              u16* __restrict__ out) {
  long idx = ((long)blockIdx.x * 256 + threadIdx.x) * 8;
  long tok = idx >> 10;
  int c = (int)(idx & 1023);
  int h = c >> 6, d0 = c & 63;
  int b = (int)(tok >> 12);
  float sq = sigmoidf_(qp[tok * 16 + h]);
  const float* sp = scum + ((long)b * 16 + h) * 64 + d0;
  uint4 o;
  o.x = (uint32_t)f2bf(sq * sp[0]) | ((uint32_t)f2bf(sq * sp[1]) << 16);
  o.y = (uint32_t)f2bf(sq * sp[2]) | ((uint32_t)f2bf(sq * sp[3]) << 16);
  o.z = (uint32_t)f2bf(sq * sp[4]) | ((uint32_t)f2bf(sq * sp[5]) << 16);
  o.w = (uint32_t)f2bf(sq * sp[6]) | ((uint32_t)f2bf(sq * sp[7]) << 16);
  *((uint4*)(out + idx)) = o;
}

// --- out_f32 = LayerNorm(a_bf16 + r_f32)*g + be ; optional bf16 copy -----
__global__ __launch_bounds__(256) void ln_res(const u16* __restrict__ a,
                                              const float* __restrict__ r,
                                              const float* __restrict__ g,
                                              const float* __restrict__ be,
                                              float* __restrict__ out,
                                              u16* __restrict__ outb) {
  long row = blockIdx.x;
  int tid = threadIdx.x;
  uint2 av = ((const uint2*)(a + row * 1024))[tid];
  float4 rv = ((const float4*)(r + row * 1024))[tid];
  float y[4];
  y[0] = bf2f((u16)(av.x & 0xffff)) + rv.x;
  y[1] = bf2f((u16)(av.x >> 16)) + rv.y;
  y[2] = bf2f((u16)(av.y & 0xffff)) + rv.z;
  y[3] = bf2f((u16)(av.y >> 16)) + rv.w;
  float s = y[0] + y[1] + y[2] + y[3];
  float q = y[0] * y[0] + y[1] * y[1] + y[2] * y[2] + y[3] * y[3];
#pragma unroll
  for (int o = 32; o > 0; o >>= 1) {
    s += __shfl_down(s, o);
    q += __shfl_down(q, o);
  }
  __shared__ float s1[4], s2[4];
  int wid = tid >> 6, lane = tid & 63;
  if (lane == 0) { s1[wid] = s; s2[wid] = q; }
  __syncthreads();
  s = s1[0] + s1[1] + s1[2] + s1[3];
  q = s2[0] + s2[1] + s2[2] + s2[3];
  float mu = s * (1.f / 1024.f);
  float var = q * (1.f / 1024.f) - mu * mu;
  float inv = rsqrtf(fmaxf(var, 0.f) + 1e-6f);
  float4 gv = ((const float4*)g)[tid], bv = ((const float4*)be)[tid];
  float o0 = gv.x * (y[0] - mu) * inv + bv.x;
  float o1 = gv.y * (y[1] - mu) * inv + bv.y;
  float o2 = gv.z * (y[2] - mu) * inv + bv.z;
  float o3 = gv.w * (y[3] - mu) * inv + bv.w;
  ((float4*)(out + row * 1024))[tid] = make_float4(o0, o1, o2, o3);
  if (outb != nullptr) {
    uint2 ob;
    ob.x = (uint32_t)f2bf(o0) | ((uint32_t)f2bf(o1) << 16);
    ob.y = (uint32_t)f2bf(o2) | ((uint32_t)f2bf(o3) << 16);
    ((uint2*)(outb + row * 1024))[tid] = ob;
  }
}

extern "C" void kernel_launch(void* const* d_in, const int* in_sizes, int n_in,
                              void* d_out, int out_size, void* d_ws,
                              size_t ws_size, hipStream_t stream) {
  const float* x   = (const float*)d_in[0];
  const float* enc = (const float*)d_in[1];
  const float* wq1 = (const float*)d_in[2];  const float* bq1 = (const float*)d_in[3];
  const float* wk1 = (const float*)d_in[4];  const float* bk1 = (const float*)d_in[5];
  const float* wv1 = (const float*)d_in[6];  const float* bv1 = (const float*)d_in[7];
  const float* wo1 = (const float*)d_in[8];  const float* bo1 = (const float*)d_in[9];
  const float* wq2 = (const float*)d_in[10]; const float* bq2 = (const float*)d_in[11];
  const float* wk2 = (const float*)d_in[12]; const float* bk2 = (const float*)d_in[13];
  const float* wv2 = (const float*)d_in[14]; const float* bv2 = (const float*)d_in[15];
  const float* wo2 = (const float*)d_in[16]; const float* bo2 = (const float*)d_in[17];
  const float* wf1 = (const float*)d_in[18]; const float* bf1 = (const float*)d_in[19];
  const float* wf2 = (const float*)d_in[20]; const float* bf2 = (const float*)d_in[21];
  const float* g1 = (const float*)d_in[22];  const float* be1 = (const float*)d_in[23];
  const float* g2 = (const float*)d_in[24];  const float* be2 = (const float*)d_in[25];
  const float* g3 = (const float*)d_in[26];  const float* be3 = (const float*)d_in[27];
  (void)in_sizes; (void)n_in; (void)out_size; (void)ws_size;

  const size_t S = (size_t)16384 * 1024;  // tokens * d_model
  float* O0 = (float*)d_out;              // out3

  char* base = (char*)d_ws;
  size_t off = 0;
  auto alloc = [&](size_t bytes) -> void* {
    void* p = base + off;
    off += (bytes + 255) & ~(size_t)255;
    return p;
  };
  u16* WT1   = (u16*)alloc((size_t)4096 * 1024 * 2);  // weight^T bf16
  u16* WT2   = (u16*)alloc((size_t)4096 * 1024 * 2);
  float* qb  = (float*)alloc((size_t)16384 * 16 * 4);
  float* kb  = (float*)alloc((size_t)16384 * 16 * 4);
  float* kvp = (float*)alloc((size_t)512 * 64 * 4);
  float* scm = (float*)alloc((size_t)4 * 16 * 64 * 4);
  u16* FA    = (u16*)alloc(S * 2);                    // bf16: v / attn / ffn_out
  u16* XB    = (u16*)alloc(S * 2);                    // bf16: x / enc / out2
  u16* FB    = (u16*)alloc(S * 2);                    // bf16: pre (attn input)
  u16* FM    = (u16*)alloc((size_t)16384 * 4096 * 2); // bf16: ffn mid (134MB)
  float* O1f = (float*)alloc(S * 4);                  // f32 out1
  float* O2f = (float*)alloc(S * 4);                  // f32 out2

  const int T = 16384;
  dim3 blk(256), gblk(512);

  // ---- MHA1 (q=k=v from x) ----
  cvt_f2b<<<16384, blk, 0, stream>>>(x, XB);
  transpose_cvt<<<dim3(32, 32), blk, 0, stream>>>(wv1, WT1, 1024, 1024);
  gemm256<0><<<dim3(4, 64), gblk, 0, stream>>>(XB, WT1, bv1, FA, T, 1024, 1024);
  proj_qk_b<<<1024, blk, 0, stream>>>(XB, wq1, bq1, wk1, bk1, qb, kb);
  kv_part<<<512, blk, 0, stream>>>(kb, FA, kvp);
  kv_finish<<<4, 64, 0, stream>>>(kvp, scm);
  premul<<<8192, blk, 0, stream>>>(qb, scm, FB);
  transpose_cvt<<<dim3(32, 32), blk, 0, stream>>>(wo1, WT1, 1024, 1024);
  gemm256<0><<<dim3(4, 64), gblk, 0, stream>>>(FB, WT1, bo1, FA, T, 1024, 1024);
  ln_res<<<16384, blk, 0, stream>>>(FA, x, g1, be1, O1f, nullptr);  // out1

  // ---- MHA2 (q from out1, k/v from enc) ----
  cvt_f2b<<<16384, blk, 0, stream>>>(enc, XB);
  transpose_cvt<<<dim3(32, 32), blk, 0, stream>>>(wv2, WT1, 1024, 1024);
  gemm256<0><<<dim3(4, 64), gblk, 0, stream>>>(XB, WT1, bv2, FA, T, 1024, 1024);
  proj_f<<<1024, blk, 0, stream>>>(O1f, wq2, bq2, qb);
  proj_b<<<1024, blk, 0, stream>>>(XB, wk2, bk2, kb);
  kv_part<<<512, blk, 0, stream>>>(kb, FA, kvp);
  kv_finish<<<4, 64, 0, stream>>>(kvp, scm);
  premul<<<8192, blk, 0, stream>>>(qb, scm, FB);
  transpose_cvt<<<dim3(32, 32), blk, 0, stream>>>(wo2, WT1, 1024, 1024);
  gemm256<0><<<dim3(4, 64), gblk, 0, stream>>>(FB, WT1, bo2, FA, T, 1024, 1024);
  ln_res<<<16384, blk, 0, stream>>>(FA, O1f, g2, be2, O2f, XB);  // out2 (+bf16)

  // ---- FFN ----
  transpose_cvt<<<dim3(128, 32), blk, 0, stream>>>(wf1, WT1, 1024, 4096);
  transpose_cvt<<<dim3(32, 128), blk, 0, stream>>>(wf2, WT2, 4096, 1024);
  gemm256<1><<<dim3(16, 64), gblk, 0, stream>>>(XB, WT1, bf1, FM, T, 4096, 1024);
  gemm256<0><<<dim3(4, 64), gblk, 0, stream>>>(FM, WT2, bf2, FA, T, 1024, 4096);
  ln_res<<<16384, blk, 0, stream>>>(FA, O2f, g3, be3, O0, nullptr);  // out3

  // outputs 1 and 2 must be zeros
  hipMemsetAsync((float*)d_out + S, 0, 2 * S * 4, stream);
}